// Round 12
// baseline (346.262 us; speedup 1.0000x reference)
//
#include <hip/hip_runtime.h>
#include <hip/hip_bf16.h>
#include <math.h>

#define HID 64
#define BK 8                      // 256 rows per bucket
#define B_WG 256                  // partition workgroups
#define KMAX 512

typedef __attribute__((ext_vector_type(4))) float f32x4;
typedef __attribute__((ext_vector_type(4))) short s16x4;
typedef unsigned char uchar;

__device__ __forceinline__ ushort f2b(float x) {
    __hip_bfloat16 h = __float2bfloat16(x);
    return *reinterpret_cast<ushort*>(&h);
}
__device__ __forceinline__ float b2f(ushort u) {
    return __uint_as_float(((unsigned)u) << 16);
}

// D = A*B + C, 16x16x16 bf16 MFMA. s_nop covers VALU-write -> MFMA-read hazard.
__device__ __forceinline__ f32x4 mfma16(s16x4 a, s16x4 b, f32x4 c) {
    asm("s_nop 1\n\tv_mfma_f32_16x16x16_bf16 %0, %1, %2, %0"
        : "+v"(c) : "v"(a), "v"(b));
    return c;
}

// ---------------------------------------------------------------------------
// feat (f32) -> bf16 copy, 8 elems/thread
// ---------------------------------------------------------------------------
__global__ __launch_bounds__(256) void cvt_bf16_kernel(const float* __restrict__ x,
                                                       ushort* __restrict__ x16, long n8)
{
    long i = (long)blockIdx.x * 256 + threadIdx.x;
    if (i >= n8) return;
    const float4* s = reinterpret_cast<const float4*>(x) + i * 2;
    float4 a = s[0], b = s[1];
    union { uint4 q; ushort s[8]; } pk;
    pk.s[0] = f2b(a.x); pk.s[1] = f2b(a.y); pk.s[2] = f2b(a.z); pk.s[3] = f2b(a.w);
    pk.s[4] = f2b(b.x); pk.s[5] = f2b(b.y); pk.s[6] = f2b(b.z); pk.s[7] = f2b(b.w);
    reinterpret_cast<uint4*>(x16)[i] = pk.q;
}

// ---------------------------------------------------------------------------
// One-time weight prep: transpose + bf16-convert the 4 per-layer matrices into
// wbuf[l][m][c][68] (c = out col, padded k). block = l*4 + m.
// ---------------------------------------------------------------------------
__global__ __launch_bounds__(256) void prep_weights(
    const float* __restrict__ nbW, const float* __restrict__ selfW,
    const float* __restrict__ a1W, ushort* __restrict__ wbuf)
{
    int b = blockIdx.x;
    int l = b >> 2, m = b & 3;
    const float* src;
    if (m == 0)      src = nbW   + (size_t)l * 4096;
    else if (m == 1) src = a1W   + (size_t)l * 8192;          // A_top
    else if (m == 2) src = selfW + (size_t)l * 4096;
    else             src = a1W   + (size_t)l * 8192 + 4096;   // A_bot
    ushort* dst = wbuf + (size_t)b * 64 * 68;
    for (int i = threadIdx.x; i < 4096; i += 256) {
        int k = i >> 6, c = i & 63;
        dst[c * 68 + k] = f2b(src[i]);
    }
}

// ---------------------------------------------------------------------------
// MFMA node MLP. Block = 256 thr (4 waves), M-tile = 128 nodes.
// Weights pre-transposed/converted in wbuf -> LDS staging is a plain memcpy.
// ---------------------------------------------------------------------------
template<bool A_FROM_REGS, bool STORE_GLOBAL>
__device__ __forceinline__ void mfma_stage(
    const s16x4 afr[2][4], const ushort (*Wt)[68], const float* bias,
    ushort (*gld)[68], int w, int l, ushort* dstg, int rbase, int n)
{
    f32x4 acc[2][4];
    #pragma unroll
    for (int ct = 0; ct < 4; ++ct) {
        float bv = bias ? bias[(ct << 4) + (l & 15)] : 0.f;
        acc[0][ct] = (f32x4){bv, bv, bv, bv};
        acc[1][ct] = (f32x4){bv, bv, bv, bv};
    }
    #pragma unroll
    for (int kc = 0; kc < 4; ++kc) {
        s16x4 a0, a1;
        if (A_FROM_REGS) {
            a0 = afr[0][kc]; a1 = afr[1][kc];
        } else {
            a0 = *(const s16x4*)&gld[w*32 +  0 + (l & 15)][((l >> 4) << 2) + (kc << 4)];
            a1 = *(const s16x4*)&gld[w*32 + 16 + (l & 15)][((l >> 4) << 2) + (kc << 4)];
        }
        #pragma unroll
        for (int ct = 0; ct < 4; ++ct) {
            s16x4 b = *(const s16x4*)&Wt[(ct << 4) + (l & 15)][((l >> 4) << 2) + (kc << 4)];
            acc[0][ct] = mfma16(a0, b, acc[0][ct]);
            acc[1][ct] = mfma16(a1, b, acc[1][ct]);
        }
    }
    asm volatile("s_nop 7\n\ts_nop 7");   // MFMA-write -> VALU-read hazard
    #pragma unroll
    for (int rt = 0; rt < 2; ++rt)
    #pragma unroll
    for (int ct = 0; ct < 4; ++ct)
    #pragma unroll
    for (int j = 0; j < 4; ++j) {
        int rloc = w*32 + rt*16 + ((l >> 4) << 2) + j;
        if (STORE_GLOBAL) {
            int rg = rbase + rloc;
            if (rg < n)
                dstg[(size_t)rg * HID + (ct << 4) + (l & 15)] = f2b(acc[rt][ct][j]);
        } else {
            gld[rloc][(ct << 4) + (l & 15)] = f2b(fmaxf(acc[rt][ct][j], 0.f));
        }
    }
}

__global__ __launch_bounds__(256) void node_mlp_mfma(
    const ushort* __restrict__ x16,
    const ushort* __restrict__ wb,     // wbuf for this layer: [4][64][68] bf16
    const float* __restrict__ b1, const float* __restrict__ b2,
    const float* __restrict__ ab,
    ushort* __restrict__ u, ushort* __restrict__ v, int n)
{
    __shared__ __align__(16) ushort Wt[4][64][68];
    __shared__ ushort gld[128][68];
    int tid = threadIdx.x;
    int l = tid & 63, w = tid >> 6;
    int rbase = blockIdx.x * 128;

    // straight memcpy: 4*64*68*2 B = 34816 B = 2176 uint4
    {
        const uint4* ws4 = reinterpret_cast<const uint4*>(wb);
        uint4* wd4 = reinterpret_cast<uint4*>(&Wt[0][0][0]);
        for (int i = tid; i < 2176; i += 256) wd4[i] = ws4[i];
    }

    s16x4 afr[2][4];
    #pragma unroll
    for (int rt = 0; rt < 2; ++rt) {
        int r = rbase + w*32 + rt*16 + (l & 15);
        int rc = min(r, n - 1);
        const ushort* xr = x16 + (size_t)rc * HID + ((l >> 4) << 2);
        #pragma unroll
        for (int kc = 0; kc < 4; ++kc)
            afr[rt][kc] = *(const s16x4*)(xr + (kc << 4));
    }
    __syncthreads();

    mfma_stage<true,  false>(afr, Wt[0], b1,      gld, w, l, nullptr, rbase, n);
    mfma_stage<false, true >(afr, Wt[1], ab,      gld, w, l, u,       rbase, n);
    mfma_stage<true,  false>(afr, Wt[2], b2,      gld, w, l, nullptr, rbase, n);
    mfma_stage<false, true >(afr, Wt[3], nullptr, gld, w, l, v,       rbase, n);
}

// ---------------------------------------------------------------------------
// CSR build, radix style: no global atomics, exclusive write segments.
// tmp payload packed to 4B: (row & 255) << 24 | col   (needs n < 2^24)
// ---------------------------------------------------------------------------
__global__ __launch_bounds__(256) void bucket_hist(const int* __restrict__ row,
                                                   int* __restrict__ hist,
                                                   int E, int K, int chunk)
{
    __shared__ int h[KMAX];
    for (int i = threadIdx.x; i < K; i += 256) h[i] = 0;
    __syncthreads();
    int w = blockIdx.x;
    int s = w * chunk, e = min(E, s + chunk);
    for (int i = s + threadIdx.x; i < e; i += 256)
        atomicAdd(&h[row[i] >> BK], 1);
    __syncthreads();
    for (int i = threadIdx.x; i < K; i += 256)
        hist[i * B_WG + w] = h[i];
}

__global__ __launch_bounds__(512) void bucket_base(const int* __restrict__ hist,
                                                   int* __restrict__ bbase,
                                                   int* __restrict__ ptr,
                                                   int K, int E, int n)
{
    __shared__ int lds[512];
    int t = threadIdx.x;
    int total = 0;
    if (t < K) {
        const int* hrow = hist + t * B_WG;
        for (int w = 0; w < B_WG; ++w) total += hrow[w];
    }
    lds[t] = total;
    __syncthreads();
    int val = total;
    for (int off = 1; off < 512; off <<= 1) {
        int tmp = (t >= off) ? lds[t - off] : 0;
        __syncthreads();
        val += tmp;
        lds[t] = val;
        __syncthreads();
    }
    if (t <= K) bbase[t] = val - total;
    if (t == 0) ptr[n] = E;
}

__global__ __launch_bounds__(B_WG) void wg_offsets(const int* __restrict__ hist,
                                                   const int* __restrict__ bbase,
                                                   int* __restrict__ offs)
{
    __shared__ int lds[B_WG];
    int b = blockIdx.x, t = threadIdx.x;
    int v = hist[b * B_WG + t];
    lds[t] = v;
    __syncthreads();
    int val = v;
    for (int off = 1; off < B_WG; off <<= 1) {
        int tmp = (t >= off) ? lds[t - off] : 0;
        __syncthreads();
        val += tmp;
        lds[t] = val;
        __syncthreads();
    }
    offs[b * B_WG + t] = bbase[b] + val - v;
}

__global__ __launch_bounds__(256) void partition_edges(const int* __restrict__ row,
                                                       const int* __restrict__ col,
                                                       const int* __restrict__ offs,
                                                       uint* __restrict__ tmp,
                                                       int E, int K, int chunk)
{
    __shared__ int cur[KMAX];
    int w = blockIdx.x;
    for (int i = threadIdx.x; i < K; i += 256)
        cur[i] = offs[i * B_WG + w];
    __syncthreads();
    int s = w * chunk, e = min(E, s + chunk);
    for (int i = s + threadIdx.x; i < e; i += 256) {
        int r = row[i], c = col[i];
        int pos = atomicAdd(&cur[r >> BK], 1);
        tmp[pos] = ((uint)(r & 255) << 24) | (uint)c;
    }
}

__global__ __launch_bounds__(256) void fine_sort(const uint* __restrict__ tmp,
                                                 const int* __restrict__ bbase,
                                                 int* __restrict__ ptr,
                                                 int* __restrict__ row_sorted,
                                                 int* __restrict__ col_sorted,
                                                 int n)
{
    __shared__ int rcnt[256];
    __shared__ int scan[256];
    __shared__ int cur[256];
    int b = blockIdx.x, t = threadIdx.x;
    int row0 = b << BK;
    rcnt[t] = 0;
    __syncthreads();
    int s = bbase[b], e = bbase[b + 1];
    for (int i = s + t; i < e; i += 256)
        atomicAdd(&rcnt[tmp[i] >> 24], 1);
    __syncthreads();
    int v = rcnt[t];
    scan[t] = v;
    __syncthreads();
    int val = v;
    for (int off = 1; off < 256; off <<= 1) {
        int tm = (t >= off) ? scan[t - off] : 0;
        __syncthreads();
        val += tm;
        scan[t] = val;
        __syncthreads();
    }
    int rstart = s + val - v;
    int r = row0 + t;
    if (r < n) ptr[r] = rstart;
    cur[t] = rstart;
    __syncthreads();
    for (int i = s + t; i < e; i += 256) {
        uint rc = tmp[i];
        int pos = atomicAdd(&cur[rc >> 24], 1);
        row_sorted[pos] = row0 | (int)(rc >> 24);
        col_sorted[pos] = (int)(rc & 0xFFFFFFu);
    }
}

// ---------------------------------------------------------------------------
// Edge mask: 8 lanes per edge, ushort8 (16B) loads, 3-stage reduce
// ---------------------------------------------------------------------------
__global__ __launch_bounds__(256) void edge_mask8(
    const ushort* __restrict__ u, const ushort* __restrict__ v,
    const float* __restrict__ w2, const float* __restrict__ b2p,
    const int* __restrict__ rows, const int* __restrict__ cols,
    float* __restrict__ mask_sorted, int E)
{
    int g = (blockIdx.x * 256 + threadIdx.x) >> 3;
    if (g >= E) return;
    int sub = threadIdx.x & 7;
    int r = rows[g], c = cols[g];
    union { uint4 q; ushort s[8]; } uu, vv;
    uu.q = *reinterpret_cast<const uint4*>(u + (size_t)r * HID + sub * 8);
    vv.q = *reinterpret_cast<const uint4*>(v + (size_t)c * HID + sub * 8);
    float4 wa = *reinterpret_cast<const float4*>(w2 + sub * 8);
    float4 wb = *reinterpret_cast<const float4*>(w2 + sub * 8 + 4);
    float p;
    p =        fmaxf(b2f(uu.s[0]) + b2f(vv.s[0]), 0.f) * wa.x;
    p = fmaf(fmaxf(b2f(uu.s[1]) + b2f(vv.s[1]), 0.f), wa.y, p);
    p = fmaf(fmaxf(b2f(uu.s[2]) + b2f(vv.s[2]), 0.f), wa.z, p);
    p = fmaf(fmaxf(b2f(uu.s[3]) + b2f(vv.s[3]), 0.f), wa.w, p);
    p = fmaf(fmaxf(b2f(uu.s[4]) + b2f(vv.s[4]), 0.f), wb.x, p);
    p = fmaf(fmaxf(b2f(uu.s[5]) + b2f(vv.s[5]), 0.f), wb.y, p);
    p = fmaf(fmaxf(b2f(uu.s[6]) + b2f(vv.s[6]), 0.f), wb.z, p);
    p = fmaf(fmaxf(b2f(uu.s[7]) + b2f(vv.s[7]), 0.f), wb.w, p);
    p += __shfl_xor(p, 1, 64);
    p += __shfl_xor(p, 2, 64);
    p += __shfl_xor(p, 4, 64);
    if (sub == 0) {
        float la = p + b2p[0];
        float s = 1.f / (1.f + __expf(-la));
        mask_sorted[g] = fminf(fmaxf(fmaf(s, 1.5f, -0.45f), 0.f), 1.f);
    }
}

__global__ __launch_bounds__(256) void rowsum_dinv(
    const float* __restrict__ mask_sorted, const int* __restrict__ ptr,
    float* __restrict__ dinv, int n)
{
    int i = blockIdx.x * 256 + threadIdx.x;
    if (i >= n) return;
    int s0 = ptr[i], s1 = ptr[i + 1];
    float s = 1e-6f;
    for (int e = s0; e < s1; ++e) s += mask_sorted[e];
    float d = 1.f / sqrtf(s);
    dinv[i] = fminf(d, 10.f);
}

// ---------------------------------------------------------------------------
// Aggregation: wave-per-node, 2 cols/lane-half, 16-col chunks (zero-padded).
// FMT: 0 = gather bf16 x rows (128 B), 1 = gather fp8-e4m3 x rows (64 B).
// Non-LAST epilogue writes res as bf16 (for out-sum / node_mlp) AND fp8
// (gather copy for next layer). LAST fuses out = feat + r1 + r2 + res.
// ---------------------------------------------------------------------------
template<int FMT, bool LAST>
__global__ __launch_bounds__(256) void agg_csr2(
    const ushort* __restrict__ x16, const uchar* __restrict__ x8,
    const float* __restrict__ mask_sorted, const float* __restrict__ dinv,
    const int* __restrict__ ptr, const int* __restrict__ col_sorted,
    ushort* __restrict__ x16_out, ushort* __restrict__ x8_out,
    const float* __restrict__ feat, const ushort* __restrict__ r1,
    const ushort* __restrict__ r2, float* __restrict__ out, int n)
{
    int wid = (blockIdx.x * 256 + threadIdx.x) >> 6;
    if (wid >= n) return;
    int lane = threadIdx.x & 63;
    int half = lane >> 5;        // 0: even cols, 1: odd cols
    int d2 = lane & 31;          // dim pair index
    int start = ptr[wid], end = ptr[wid + 1];
    int deg = end - start;
    const ushort* xb16 = x16 + d2 * 2;       // col offset = c*HID ushorts
    const uchar*  xb8  = x8 + d2 * 2;        // col offset = c*64 bytes
    float ax = 0.f, ay = 0.f;

    for (int base = 0; base < deg; base += 64) {
        int mcnt = min(64, deg - base);
        int cc = 0; float wv = 0.f;
        if (lane < mcnt) {
            cc = col_sorted[start + base + lane];
            wv = mask_sorted[start + base + lane] * dinv[cc];
        }
        int m16 = (mcnt + 15) & ~15;        // pad; extra lanes carry w=0
        for (int j = 0; j < m16; j += 16) {
            int jj = j + half;
            int   c0 = __shfl(cc, jj,      64);
            int   c1 = __shfl(cc, jj + 2,  64);
            int   c2 = __shfl(cc, jj + 4,  64);
            int   c3 = __shfl(cc, jj + 6,  64);
            int   c4 = __shfl(cc, jj + 8,  64);
            int   c5 = __shfl(cc, jj + 10, 64);
            int   c6 = __shfl(cc, jj + 12, 64);
            int   c7 = __shfl(cc, jj + 14, 64);
            float w0 = __shfl(wv, jj,      64);
            float w1 = __shfl(wv, jj + 2,  64);
            float w2 = __shfl(wv, jj + 4,  64);
            float w3 = __shfl(wv, jj + 6,  64);
            float w4 = __shfl(wv, jj + 8,  64);
            float w5 = __shfl(wv, jj + 10, 64);
            float w6 = __shfl(wv, jj + 12, 64);
            float w7 = __shfl(wv, jj + 14, 64);
            if (FMT == 0) {
                uint p0 = *reinterpret_cast<const uint*>(xb16 + (size_t)c0 * HID);
                uint p1 = *reinterpret_cast<const uint*>(xb16 + (size_t)c1 * HID);
                uint p2 = *reinterpret_cast<const uint*>(xb16 + (size_t)c2 * HID);
                uint p3 = *reinterpret_cast<const uint*>(xb16 + (size_t)c3 * HID);
                uint p4 = *reinterpret_cast<const uint*>(xb16 + (size_t)c4 * HID);
                uint p5 = *reinterpret_cast<const uint*>(xb16 + (size_t)c5 * HID);
                uint p6 = *reinterpret_cast<const uint*>(xb16 + (size_t)c6 * HID);
                uint p7 = *reinterpret_cast<const uint*>(xb16 + (size_t)c7 * HID);
                ax = fmaf(w0, b2f((ushort)p0), ax); ay = fmaf(w0, b2f((ushort)(p0 >> 16)), ay);
                ax = fmaf(w1, b2f((ushort)p1), ax); ay = fmaf(w1, b2f((ushort)(p1 >> 16)), ay);
                ax = fmaf(w2, b2f((ushort)p2), ax); ay = fmaf(w2, b2f((ushort)(p2 >> 16)), ay);
                ax = fmaf(w3, b2f((ushort)p3), ax); ay = fmaf(w3, b2f((ushort)(p3 >> 16)), ay);
                ax = fmaf(w4, b2f((ushort)p4), ax); ay = fmaf(w4, b2f((ushort)(p4 >> 16)), ay);
                ax = fmaf(w5, b2f((ushort)p5), ax); ay = fmaf(w5, b2f((ushort)(p5 >> 16)), ay);
                ax = fmaf(w6, b2f((ushort)p6), ax); ay = fmaf(w6, b2f((ushort)(p6 >> 16)), ay);
                ax = fmaf(w7, b2f((ushort)p7), ax); ay = fmaf(w7, b2f((ushort)(p7 >> 16)), ay);
            } else {
                uint p0 = *reinterpret_cast<const ushort*>(xb8 + (size_t)c0 * 64);
                uint p1 = *reinterpret_cast<const ushort*>(xb8 + (size_t)c1 * 64);
                uint p2 = *reinterpret_cast<const ushort*>(xb8 + (size_t)c2 * 64);
                uint p3 = *reinterpret_cast<const ushort*>(xb8 + (size_t)c3 * 64);
                uint p4 = *reinterpret_cast<const ushort*>(xb8 + (size_t)c4 * 64);
                uint p5 = *reinterpret_cast<const ushort*>(xb8 + (size_t)c5 * 64);
                uint p6 = *reinterpret_cast<const ushort*>(xb8 + (size_t)c6 * 64);
                uint p7 = *reinterpret_cast<const ushort*>(xb8 + (size_t)c7 * 64);
                ax = fmaf(w0, __builtin_amdgcn_cvt_f32_fp8(p0, 0), ax);
                ay = fmaf(w0, __builtin_amdgcn_cvt_f32_fp8(p0, 1), ay);
                ax = fmaf(w1, __builtin_amdgcn_cvt_f32_fp8(p1, 0), ax);
                ay = fmaf(w1, __builtin_amdgcn_cvt_f32_fp8(p1, 1), ay);
                ax = fmaf(w2, __builtin_amdgcn_cvt_f32_fp8(p2, 0), ax);
                ay = fmaf(w2, __builtin_amdgcn_cvt_f32_fp8(p2, 1), ay);
                ax = fmaf(w3, __builtin_amdgcn_cvt_f32_fp8(p3, 0), ax);
                ay = fmaf(w3, __builtin_amdgcn_cvt_f32_fp8(p3, 1), ay);
                ax = fmaf(w4, __builtin_amdgcn_cvt_f32_fp8(p4, 0), ax);
                ay = fmaf(w4, __builtin_amdgcn_cvt_f32_fp8(p4, 1), ay);
                ax = fmaf(w5, __builtin_amdgcn_cvt_f32_fp8(p5, 0), ax);
                ay = fmaf(w5, __builtin_amdgcn_cvt_f32_fp8(p5, 1), ay);
                ax = fmaf(w6, __builtin_amdgcn_cvt_f32_fp8(p6, 0), ax);
                ay = fmaf(w6, __builtin_amdgcn_cvt_f32_fp8(p6, 1), ay);
                ax = fmaf(w7, __builtin_amdgcn_cvt_f32_fp8(p7, 0), ax);
                ay = fmaf(w7, __builtin_amdgcn_cvt_f32_fp8(p7, 1), ay);
            }
        }
    }
    // combine even/odd halves
    ax += __shfl_xor(ax, 32, 64);
    ay += __shfl_xor(ay, 32, 64);
    if (half == 0) {
        float dv = dinv[wid];
        float rx = ax * dv, ry = ay * dv;
        size_t o2 = (size_t)wid * 32 + d2;
        if (LAST) {
            float2 f = reinterpret_cast<const float2*>(feat)[o2];
            uint a1 = reinterpret_cast<const uint*>(r1)[o2];
            uint a2 = reinterpret_cast<const uint*>(r2)[o2];
            float2 o;
            o.x = f.x + b2f((ushort)a1) + b2f((ushort)a2) + rx;
            o.y = f.y + b2f((ushort)(a1 >> 16)) + b2f((ushort)(a2 >> 16)) + ry;
            reinterpret_cast<float2*>(out)[o2] = o;
        } else {
            uint pk = (uint)f2b(rx) | ((uint)f2b(ry) << 16);
            reinterpret_cast<uint*>(x16_out)[o2] = pk;
            int pk8 = __builtin_amdgcn_cvt_pk_fp8_f32(rx, ry, 0, false);
            x8_out[o2] = (ushort)pk8;
        }
    }
}

// ---------------------------------------------------------------------------

extern "C" void kernel_launch(void* const* d_in, const int* in_sizes, int n_in,
                              void* d_out, int out_size, void* d_ws, size_t ws_size,
                              hipStream_t stream)
{
    const float* feat  = (const float*)d_in[0];
    const float* nbW   = (const float*)d_in[1];
    const float* nbb   = (const float*)d_in[2];
    const float* selfW = (const float*)d_in[3];
    const float* selfb = (const float*)d_in[4];
    const float* a1W   = (const float*)d_in[5];
    const float* a1b   = (const float*)d_in[6];
    const float* a2W   = (const float*)d_in[7];
    const float* a2b   = (const float*)d_in[8];
    const int*   row   = (const int*)d_in[9];
    const int*   col   = (const int*)d_in[10];
    float* out = (float*)d_out;

    const int n = in_sizes[0] / HID;
    const int E = in_sizes[9];
    const int L = in_sizes[1] / (HID * HID);
    const size_t NH = (size_t)n * HID;
    const int K = (n + 255) >> BK;
    const int chunk = (E + B_WG - 1) / B_WG;

    char* p = (char*)d_ws;
    ushort* u          = (ushort*)p; p += NH * 2;
    ushort* v          = (ushort*)p; p += NH * 2;
    ushort* xf         = (ushort*)p; p += NH * 2;   // bf16(feat)
    ushort* r1         = (ushort*)p; p += NH * 2;   // res layer 1 (bf16)
    ushort* r2         = (ushort*)p; p += NH * 2;   // res layer 2 (bf16)
    ushort* wbuf       = (ushort*)p; p += (size_t)L * 4 * 64 * 68 * 2;
    uchar*  r1_8       = (uchar*)p;  p += NH;       // res layer 1 (fp8)
    uchar*  r2_8       = (uchar*)p;  p += NH;       // res layer 2 (fp8)
    float* dinv        = (float*)p;  p += (size_t)n * 4;
    float* mask_sorted = (float*)p;  p += (size_t)E * 4;
    int*   col_sorted  = (int*)p;    p += (size_t)E * 4;
    int*   row_sorted  = (int*)p;    p += (size_t)E * 4;
    uint*  tmp_rc      = (uint*)p;   p += (size_t)E * 4;
    int*   ptr         = (int*)p;    p += (size_t)(n + 1) * 4;
    int*   hist        = (int*)p;    p += (size_t)KMAX * B_WG * 4;
    int*   offs        = (int*)p;    p += (size_t)KMAX * B_WG * 4;
    int*   bbase       = (int*)p;    p += 1024 * 4;

    const int wBlocks = (int)(((size_t)n * 64 + 255) / 256);
    const int mBlocks = (E + 31) / 32;
    const int nodeBlocks = (n + 127) / 128;

    // ---- one-time prep: CSR radix partition + weight transpose + x bf16 ----
    prep_weights<<<4 * L, 256, 0, stream>>>(nbW, selfW, a1W, wbuf);
    bucket_hist<<<B_WG, 256, 0, stream>>>(row, hist, E, K, chunk);
    bucket_base<<<1, 512, 0, stream>>>(hist, bbase, ptr, K, E, n);
    wg_offsets<<<K, B_WG, 0, stream>>>(hist, bbase, offs);
    partition_edges<<<B_WG, 256, 0, stream>>>(row, col, offs, tmp_rc, E, K, chunk);
    fine_sort<<<K, 256, 0, stream>>>(tmp_rc, bbase, ptr, row_sorted, col_sorted, n);
    cvt_bf16_kernel<<<(int)((NH / 8 + 255) / 256), 256, 0, stream>>>(feat, xf, (long)(NH / 8));

    const ushort* x_in = xf;
    for (int l = 0; l < L; ++l) {
        node_mlp_mfma<<<nodeBlocks, 256, 0, stream>>>(
            x_in, wbuf + (size_t)l * 4 * 64 * 68,
            nbb + (size_t)l * HID, selfb + (size_t)l * HID,
            a1b + (size_t)l * HID,
            u, v, n);

        edge_mask8<<<mBlocks, 256, 0, stream>>>(
            u, v, a2W + (size_t)l * HID, a2b + l,
            row_sorted, col_sorted, mask_sorted, E);

        rowsum_dinv<<<(n + 255) / 256, 256, 0, stream>>>(mask_sorted, ptr, dinv, n);

        if (l == 0) {
            agg_csr2<0, false><<<wBlocks, 256, 0, stream>>>(
                xf, nullptr, mask_sorted, dinv, ptr, col_sorted,
                r1, (ushort*)r1_8, nullptr, nullptr, nullptr, nullptr, n);
            x_in = r1;
        } else if (l < L - 1) {
            agg_csr2<1, false><<<wBlocks, 256, 0, stream>>>(
                nullptr, r1_8, mask_sorted, dinv, ptr, col_sorted,
                r2, (ushort*)r2_8, nullptr, nullptr, nullptr, nullptr, n);
            x_in = r2;
        } else {
            agg_csr2<1, true><<<wBlocks, 256, 0, stream>>>(
                nullptr, r2_8, mask_sorted, dinv, ptr, col_sorted,
                nullptr, nullptr, feat, r1, r2, out, n);
        }
    }
}

// Round 13
// 342.059 us; speedup vs baseline: 1.0123x; 1.0123x over previous
//
#include <hip/hip_runtime.h>
#include <hip/hip_bf16.h>
#include <math.h>

#define HID 64
#define BK 8                      // 256 rows per bucket
#define B_WG 256                  // partition workgroups
#define KMAX 512

typedef __attribute__((ext_vector_type(4))) float f32x4;
typedef __attribute__((ext_vector_type(4))) short s16x4;
typedef unsigned char uchar;

__device__ __forceinline__ ushort f2b(float x) {
    __hip_bfloat16 h = __float2bfloat16(x);
    return *reinterpret_cast<ushort*>(&h);
}
__device__ __forceinline__ float b2f(ushort u) {
    return __uint_as_float(((unsigned)u) << 16);
}
__device__ __forceinline__ uchar f2fp8(float x) {
    int pk = __builtin_amdgcn_cvt_pk_fp8_f32(x, x, 0, false);
    return (uchar)(pk & 0xFF);
}

// D = A*B + C, 16x16x16 bf16 MFMA. s_nop covers VALU-write -> MFMA-read hazard.
__device__ __forceinline__ f32x4 mfma16(s16x4 a, s16x4 b, f32x4 c) {
    asm("s_nop 1\n\tv_mfma_f32_16x16x16_bf16 %0, %1, %2, %0"
        : "+v"(c) : "v"(a), "v"(b));
    return c;
}

// ---------------------------------------------------------------------------
// feat (f32) -> bf16 copy, 8 elems/thread
// ---------------------------------------------------------------------------
__global__ __launch_bounds__(256) void cvt_bf16_kernel(const float* __restrict__ x,
                                                       ushort* __restrict__ x16, long n8)
{
    long i = (long)blockIdx.x * 256 + threadIdx.x;
    if (i >= n8) return;
    const float4* s = reinterpret_cast<const float4*>(x) + i * 2;
    float4 a = s[0], b = s[1];
    union { uint4 q; ushort s[8]; } pk;
    pk.s[0] = f2b(a.x); pk.s[1] = f2b(a.y); pk.s[2] = f2b(a.z); pk.s[3] = f2b(a.w);
    pk.s[4] = f2b(b.x); pk.s[5] = f2b(b.y); pk.s[6] = f2b(b.z); pk.s[7] = f2b(b.w);
    reinterpret_cast<uint4*>(x16)[i] = pk.q;
}

// ---------------------------------------------------------------------------
// One-time weight prep: transpose + bf16-convert the 4 per-layer matrices into
// wbuf[l][m][c][68] (c = out col, padded k). block = l*4 + m.
// ---------------------------------------------------------------------------
__global__ __launch_bounds__(256) void prep_weights(
    const float* __restrict__ nbW, const float* __restrict__ selfW,
    const float* __restrict__ a1W, ushort* __restrict__ wbuf)
{
    int b = blockIdx.x;
    int l = b >> 2, m = b & 3;
    const float* src;
    if (m == 0)      src = nbW   + (size_t)l * 4096;
    else if (m == 1) src = a1W   + (size_t)l * 8192;          // A_top
    else if (m == 2) src = selfW + (size_t)l * 4096;
    else             src = a1W   + (size_t)l * 8192 + 4096;   // A_bot
    ushort* dst = wbuf + (size_t)b * 64 * 68;
    for (int i = threadIdx.x; i < 4096; i += 256) {
        int k = i >> 6, c = i & 63;
        dst[c * 68 + k] = f2b(src[i]);
    }
}

// ---------------------------------------------------------------------------
// MFMA node MLP. Block = 256 thr (4 waves), M-tile = 128 nodes.
// STORE: 0 = LDS relu (hidden), 1 = global bf16, 2 = global fp8-e4m3
// ---------------------------------------------------------------------------
template<bool A_FROM_REGS, int STORE>
__device__ __forceinline__ void mfma_stage(
    const s16x4 afr[2][4], const ushort (*Wt)[68], const float* bias,
    ushort (*gld)[68], int w, int l, void* dstg, int rbase, int n)
{
    f32x4 acc[2][4];
    #pragma unroll
    for (int ct = 0; ct < 4; ++ct) {
        float bv = bias ? bias[(ct << 4) + (l & 15)] : 0.f;
        acc[0][ct] = (f32x4){bv, bv, bv, bv};
        acc[1][ct] = (f32x4){bv, bv, bv, bv};
    }
    #pragma unroll
    for (int kc = 0; kc < 4; ++kc) {
        s16x4 a0, a1;
        if (A_FROM_REGS) {
            a0 = afr[0][kc]; a1 = afr[1][kc];
        } else {
            a0 = *(const s16x4*)&gld[w*32 +  0 + (l & 15)][((l >> 4) << 2) + (kc << 4)];
            a1 = *(const s16x4*)&gld[w*32 + 16 + (l & 15)][((l >> 4) << 2) + (kc << 4)];
        }
        #pragma unroll
        for (int ct = 0; ct < 4; ++ct) {
            s16x4 b = *(const s16x4*)&Wt[(ct << 4) + (l & 15)][((l >> 4) << 2) + (kc << 4)];
            acc[0][ct] = mfma16(a0, b, acc[0][ct]);
            acc[1][ct] = mfma16(a1, b, acc[1][ct]);
        }
    }
    asm volatile("s_nop 7\n\ts_nop 7");   // MFMA-write -> VALU-read hazard
    #pragma unroll
    for (int rt = 0; rt < 2; ++rt)
    #pragma unroll
    for (int ct = 0; ct < 4; ++ct)
    #pragma unroll
    for (int j = 0; j < 4; ++j) {
        int rloc = w*32 + rt*16 + ((l >> 4) << 2) + j;
        int colx = (ct << 4) + (l & 15);
        if (STORE != 0) {
            int rg = rbase + rloc;
            if (rg < n) {
                if (STORE == 1)
                    ((ushort*)dstg)[(size_t)rg * HID + colx] = f2b(acc[rt][ct][j]);
                else
                    ((uchar*)dstg)[(size_t)rg * HID + colx] = f2fp8(acc[rt][ct][j]);
            }
        } else {
            gld[rloc][colx] = f2b(fmaxf(acc[rt][ct][j], 0.f));
        }
    }
}

__global__ __launch_bounds__(256) void node_mlp_mfma(
    const ushort* __restrict__ x16,
    const ushort* __restrict__ wb,     // wbuf for this layer: [4][64][68] bf16
    const float* __restrict__ b1, const float* __restrict__ b2,
    const float* __restrict__ ab,
    ushort* __restrict__ u, uchar* __restrict__ v8, int n)
{
    __shared__ __align__(16) ushort Wt[4][64][68];
    __shared__ ushort gld[128][68];
    int tid = threadIdx.x;
    int l = tid & 63, w = tid >> 6;
    int rbase = blockIdx.x * 128;

    // straight memcpy: 4*64*68*2 B = 34816 B = 2176 uint4
    {
        const uint4* ws4 = reinterpret_cast<const uint4*>(wb);
        uint4* wd4 = reinterpret_cast<uint4*>(&Wt[0][0][0]);
        for (int i = tid; i < 2176; i += 256) wd4[i] = ws4[i];
    }

    s16x4 afr[2][4];
    #pragma unroll
    for (int rt = 0; rt < 2; ++rt) {
        int r = rbase + w*32 + rt*16 + (l & 15);
        int rc = min(r, n - 1);
        const ushort* xr = x16 + (size_t)rc * HID + ((l >> 4) << 2);
        #pragma unroll
        for (int kc = 0; kc < 4; ++kc)
            afr[rt][kc] = *(const s16x4*)(xr + (kc << 4));
    }
    __syncthreads();

    mfma_stage<true,  0>(afr, Wt[0], b1,      gld, w, l, nullptr, rbase, n);
    mfma_stage<false, 1>(afr, Wt[1], ab,      gld, w, l, u,       rbase, n);
    mfma_stage<true,  0>(afr, Wt[2], b2,      gld, w, l, nullptr, rbase, n);
    mfma_stage<false, 2>(afr, Wt[3], nullptr, gld, w, l, v8,      rbase, n);
}

// ---------------------------------------------------------------------------
// CSR build, radix style: no global atomics, exclusive write segments.
// tmp payload packed to 4B: (row & 255) << 24 | col   (needs n < 2^24)
// ---------------------------------------------------------------------------
__global__ __launch_bounds__(256) void bucket_hist(const int* __restrict__ row,
                                                   int* __restrict__ hist,
                                                   int E, int K, int chunk)
{
    __shared__ int h[KMAX];
    for (int i = threadIdx.x; i < K; i += 256) h[i] = 0;
    __syncthreads();
    int w = blockIdx.x;
    int s = w * chunk, e = min(E, s + chunk);
    for (int i = s + threadIdx.x; i < e; i += 256)
        atomicAdd(&h[row[i] >> BK], 1);
    __syncthreads();
    for (int i = threadIdx.x; i < K; i += 256)
        hist[i * B_WG + w] = h[i];
}

__global__ __launch_bounds__(512) void bucket_base(const int* __restrict__ hist,
                                                   int* __restrict__ bbase,
                                                   int* __restrict__ ptr,
                                                   int K, int E, int n)
{
    __shared__ int lds[512];
    int t = threadIdx.x;
    int total = 0;
    if (t < K) {
        const int* hrow = hist + t * B_WG;
        for (int w = 0; w < B_WG; ++w) total += hrow[w];
    }
    lds[t] = total;
    __syncthreads();
    int val = total;
    for (int off = 1; off < 512; off <<= 1) {
        int tmp = (t >= off) ? lds[t - off] : 0;
        __syncthreads();
        val += tmp;
        lds[t] = val;
        __syncthreads();
    }
    if (t <= K) bbase[t] = val - total;
    if (t == 0) ptr[n] = E;
}

__global__ __launch_bounds__(B_WG) void wg_offsets(const int* __restrict__ hist,
                                                   const int* __restrict__ bbase,
                                                   int* __restrict__ offs)
{
    __shared__ int lds[B_WG];
    int b = blockIdx.x, t = threadIdx.x;
    int v = hist[b * B_WG + t];
    lds[t] = v;
    __syncthreads();
    int val = v;
    for (int off = 1; off < B_WG; off <<= 1) {
        int tmp = (t >= off) ? lds[t - off] : 0;
        __syncthreads();
        val += tmp;
        lds[t] = val;
        __syncthreads();
    }
    offs[b * B_WG + t] = bbase[b] + val - v;
}

__global__ __launch_bounds__(256) void partition_edges(const int* __restrict__ row,
                                                       const int* __restrict__ col,
                                                       const int* __restrict__ offs,
                                                       uint* __restrict__ tmp,
                                                       int E, int K, int chunk)
{
    __shared__ int cur[KMAX];
    int w = blockIdx.x;
    for (int i = threadIdx.x; i < K; i += 256)
        cur[i] = offs[i * B_WG + w];
    __syncthreads();
    int s = w * chunk, e = min(E, s + chunk);
    for (int i = s + threadIdx.x; i < e; i += 256) {
        int r = row[i], c = col[i];
        int pos = atomicAdd(&cur[r >> BK], 1);
        tmp[pos] = ((uint)(r & 255) << 24) | (uint)c;
    }
}

__global__ __launch_bounds__(256) void fine_sort(const uint* __restrict__ tmp,
                                                 const int* __restrict__ bbase,
                                                 int* __restrict__ ptr,
                                                 int* __restrict__ row_sorted,
                                                 int* __restrict__ col_sorted,
                                                 int n)
{
    __shared__ int rcnt[256];
    __shared__ int scan[256];
    __shared__ int cur[256];
    int b = blockIdx.x, t = threadIdx.x;
    int row0 = b << BK;
    rcnt[t] = 0;
    __syncthreads();
    int s = bbase[b], e = bbase[b + 1];
    for (int i = s + t; i < e; i += 256)
        atomicAdd(&rcnt[tmp[i] >> 24], 1);
    __syncthreads();
    int v = rcnt[t];
    scan[t] = v;
    __syncthreads();
    int val = v;
    for (int off = 1; off < 256; off <<= 1) {
        int tm = (t >= off) ? scan[t - off] : 0;
        __syncthreads();
        val += tm;
        scan[t] = val;
        __syncthreads();
    }
    int rstart = s + val - v;
    int r = row0 + t;
    if (r < n) ptr[r] = rstart;
    cur[t] = rstart;
    __syncthreads();
    for (int i = s + t; i < e; i += 256) {
        uint rc = tmp[i];
        int pos = atomicAdd(&cur[rc >> 24], 1);
        row_sorted[pos] = row0 | (int)(rc >> 24);
        col_sorted[pos] = (int)(rc & 0xFFFFFFu);
    }
}

// ---------------------------------------------------------------------------
// Edge mask: 8 lanes per edge. u bf16 (16B/lane, row-sorted -> cached),
// v fp8-e4m3 (8B/lane -> one 64B line per edge). 3-stage reduce.
// ---------------------------------------------------------------------------
__global__ __launch_bounds__(256) void edge_mask8(
    const ushort* __restrict__ u, const uchar* __restrict__ v8,
    const float* __restrict__ w2, const float* __restrict__ b2p,
    const int* __restrict__ rows, const int* __restrict__ cols,
    float* __restrict__ mask_sorted, int E)
{
    int g = (blockIdx.x * 256 + threadIdx.x) >> 3;
    if (g >= E) return;
    int sub = threadIdx.x & 7;
    int r = rows[g], c = cols[g];
    union { uint4 q; ushort s[8]; } uu;
    uu.q = *reinterpret_cast<const uint4*>(u + (size_t)r * HID + sub * 8);
    uint2 vv = *reinterpret_cast<const uint2*>(v8 + (size_t)c * HID + sub * 8);
    float4 wa = *reinterpret_cast<const float4*>(w2 + sub * 8);
    float4 wb = *reinterpret_cast<const float4*>(w2 + sub * 8 + 4);
    float v0 = __builtin_amdgcn_cvt_f32_fp8(vv.x, 0);
    float v1 = __builtin_amdgcn_cvt_f32_fp8(vv.x, 1);
    float v2 = __builtin_amdgcn_cvt_f32_fp8(vv.x, 2);
    float v3 = __builtin_amdgcn_cvt_f32_fp8(vv.x, 3);
    float v4 = __builtin_amdgcn_cvt_f32_fp8(vv.y, 0);
    float v5 = __builtin_amdgcn_cvt_f32_fp8(vv.y, 1);
    float v6 = __builtin_amdgcn_cvt_f32_fp8(vv.y, 2);
    float v7 = __builtin_amdgcn_cvt_f32_fp8(vv.y, 3);
    float p;
    p =      fmaxf(b2f(uu.s[0]) + v0, 0.f) * wa.x;
    p = fmaf(fmaxf(b2f(uu.s[1]) + v1, 0.f), wa.y, p);
    p = fmaf(fmaxf(b2f(uu.s[2]) + v2, 0.f), wa.z, p);
    p = fmaf(fmaxf(b2f(uu.s[3]) + v3, 0.f), wa.w, p);
    p = fmaf(fmaxf(b2f(uu.s[4]) + v4, 0.f), wb.x, p);
    p = fmaf(fmaxf(b2f(uu.s[5]) + v5, 0.f), wb.y, p);
    p = fmaf(fmaxf(b2f(uu.s[6]) + v6, 0.f), wb.z, p);
    p = fmaf(fmaxf(b2f(uu.s[7]) + v7, 0.f), wb.w, p);
    p += __shfl_xor(p, 1, 64);
    p += __shfl_xor(p, 2, 64);
    p += __shfl_xor(p, 4, 64);
    if (sub == 0) {
        float la = p + b2p[0];
        float s = 1.f / (1.f + __expf(-la));
        mask_sorted[g] = fminf(fmaxf(fmaf(s, 1.5f, -0.45f), 0.f), 1.f);
    }
}

__global__ __launch_bounds__(256) void rowsum_dinv(
    const float* __restrict__ mask_sorted, const int* __restrict__ ptr,
    float* __restrict__ dinv, int n)
{
    int i = blockIdx.x * 256 + threadIdx.x;
    if (i >= n) return;
    int s0 = ptr[i], s1 = ptr[i + 1];
    float s = 1e-6f;
    for (int e = s0; e < s1; ++e) s += mask_sorted[e];
    float d = 1.f / sqrtf(s);
    dinv[i] = fminf(d, 10.f);
}

// ---------------------------------------------------------------------------
// Aggregation: wave-per-node, 2 cols/lane-half, 16-col chunks (zero-padded).
// FMT: 0 = gather bf16 x rows (128 B), 1 = gather fp8-e4m3 x rows (64 B).
// Non-LAST epilogue writes res bf16 + fp8 copy. LAST fuses out = feat+r1+r2+res.
// ---------------------------------------------------------------------------
template<int FMT, bool LAST>
__global__ __launch_bounds__(256) void agg_csr2(
    const ushort* __restrict__ x16, const uchar* __restrict__ x8,
    const float* __restrict__ mask_sorted, const float* __restrict__ dinv,
    const int* __restrict__ ptr, const int* __restrict__ col_sorted,
    ushort* __restrict__ x16_out, ushort* __restrict__ x8_out,
    const float* __restrict__ feat, const ushort* __restrict__ r1,
    const ushort* __restrict__ r2, float* __restrict__ out, int n)
{
    int wid = (blockIdx.x * 256 + threadIdx.x) >> 6;
    if (wid >= n) return;
    int lane = threadIdx.x & 63;
    int half = lane >> 5;        // 0: even cols, 1: odd cols
    int d2 = lane & 31;          // dim pair index
    int start = ptr[wid], end = ptr[wid + 1];
    int deg = end - start;
    const ushort* xb16 = x16 + d2 * 2;       // col offset = c*HID ushorts
    const uchar*  xb8  = x8 + d2 * 2;        // col offset = c*64 bytes
    float ax = 0.f, ay = 0.f;

    for (int base = 0; base < deg; base += 64) {
        int mcnt = min(64, deg - base);
        int cc = 0; float wv = 0.f;
        if (lane < mcnt) {
            cc = col_sorted[start + base + lane];
            wv = mask_sorted[start + base + lane] * dinv[cc];
        }
        int m16 = (mcnt + 15) & ~15;        // pad; extra lanes carry w=0
        for (int j = 0; j < m16; j += 16) {
            int jj = j + half;
            int   c0 = __shfl(cc, jj,      64);
            int   c1 = __shfl(cc, jj + 2,  64);
            int   c2 = __shfl(cc, jj + 4,  64);
            int   c3 = __shfl(cc, jj + 6,  64);
            int   c4 = __shfl(cc, jj + 8,  64);
            int   c5 = __shfl(cc, jj + 10, 64);
            int   c6 = __shfl(cc, jj + 12, 64);
            int   c7 = __shfl(cc, jj + 14, 64);
            float w0 = __shfl(wv, jj,      64);
            float w1 = __shfl(wv, jj + 2,  64);
            float w2 = __shfl(wv, jj + 4,  64);
            float w3 = __shfl(wv, jj + 6,  64);
            float w4 = __shfl(wv, jj + 8,  64);
            float w5 = __shfl(wv, jj + 10, 64);
            float w6 = __shfl(wv, jj + 12, 64);
            float w7 = __shfl(wv, jj + 14, 64);
            if (FMT == 0) {
                uint p0 = *reinterpret_cast<const uint*>(xb16 + (size_t)c0 * HID);
                uint p1 = *reinterpret_cast<const uint*>(xb16 + (size_t)c1 * HID);
                uint p2 = *reinterpret_cast<const uint*>(xb16 + (size_t)c2 * HID);
                uint p3 = *reinterpret_cast<const uint*>(xb16 + (size_t)c3 * HID);
                uint p4 = *reinterpret_cast<const uint*>(xb16 + (size_t)c4 * HID);
                uint p5 = *reinterpret_cast<const uint*>(xb16 + (size_t)c5 * HID);
                uint p6 = *reinterpret_cast<const uint*>(xb16 + (size_t)c6 * HID);
                uint p7 = *reinterpret_cast<const uint*>(xb16 + (size_t)c7 * HID);
                ax = fmaf(w0, b2f((ushort)p0), ax); ay = fmaf(w0, b2f((ushort)(p0 >> 16)), ay);
                ax = fmaf(w1, b2f((ushort)p1), ax); ay = fmaf(w1, b2f((ushort)(p1 >> 16)), ay);
                ax = fmaf(w2, b2f((ushort)p2), ax); ay = fmaf(w2, b2f((ushort)(p2 >> 16)), ay);
                ax = fmaf(w3, b2f((ushort)p3), ax); ay = fmaf(w3, b2f((ushort)(p3 >> 16)), ay);
                ax = fmaf(w4, b2f((ushort)p4), ax); ay = fmaf(w4, b2f((ushort)(p4 >> 16)), ay);
                ax = fmaf(w5, b2f((ushort)p5), ax); ay = fmaf(w5, b2f((ushort)(p5 >> 16)), ay);
                ax = fmaf(w6, b2f((ushort)p6), ax); ay = fmaf(w6, b2f((ushort)(p6 >> 16)), ay);
                ax = fmaf(w7, b2f((ushort)p7), ax); ay = fmaf(w7, b2f((ushort)(p7 >> 16)), ay);
            } else {
                uint p0 = *reinterpret_cast<const ushort*>(xb8 + (size_t)c0 * 64);
                uint p1 = *reinterpret_cast<const ushort*>(xb8 + (size_t)c1 * 64);
                uint p2 = *reinterpret_cast<const ushort*>(xb8 + (size_t)c2 * 64);
                uint p3 = *reinterpret_cast<const ushort*>(xb8 + (size_t)c3 * 64);
                uint p4 = *reinterpret_cast<const ushort*>(xb8 + (size_t)c4 * 64);
                uint p5 = *reinterpret_cast<const ushort*>(xb8 + (size_t)c5 * 64);
                uint p6 = *reinterpret_cast<const ushort*>(xb8 + (size_t)c6 * 64);
                uint p7 = *reinterpret_cast<const ushort*>(xb8 + (size_t)c7 * 64);
                ax = fmaf(w0, __builtin_amdgcn_cvt_f32_fp8(p0, 0), ax);
                ay = fmaf(w0, __builtin_amdgcn_cvt_f32_fp8(p0, 1), ay);
                ax = fmaf(w1, __builtin_amdgcn_cvt_f32_fp8(p1, 0), ax);
                ay = fmaf(w1, __builtin_amdgcn_cvt_f32_fp8(p1, 1), ay);
                ax = fmaf(w2, __builtin_amdgcn_cvt_f32_fp8(p2, 0), ax);
                ay = fmaf(w2, __builtin_amdgcn_cvt_f32_fp8(p2, 1), ay);
                ax = fmaf(w3, __builtin_amdgcn_cvt_f32_fp8(p3, 0), ax);
                ay = fmaf(w3, __builtin_amdgcn_cvt_f32_fp8(p3, 1), ay);
                ax = fmaf(w4, __builtin_amdgcn_cvt_f32_fp8(p4, 0), ax);
                ay = fmaf(w4, __builtin_amdgcn_cvt_f32_fp8(p4, 1), ay);
                ax = fmaf(w5, __builtin_amdgcn_cvt_f32_fp8(p5, 0), ax);
                ay = fmaf(w5, __builtin_amdgcn_cvt_f32_fp8(p5, 1), ay);
                ax = fmaf(w6, __builtin_amdgcn_cvt_f32_fp8(p6, 0), ax);
                ay = fmaf(w6, __builtin_amdgcn_cvt_f32_fp8(p6, 1), ay);
                ax = fmaf(w7, __builtin_amdgcn_cvt_f32_fp8(p7, 0), ax);
                ay = fmaf(w7, __builtin_amdgcn_cvt_f32_fp8(p7, 1), ay);
            }
        }
    }
    // combine even/odd halves
    ax += __shfl_xor(ax, 32, 64);
    ay += __shfl_xor(ay, 32, 64);
    if (half == 0) {
        float dv = dinv[wid];
        float rx = ax * dv, ry = ay * dv;
        size_t o2 = (size_t)wid * 32 + d2;
        if (LAST) {
            float2 f = reinterpret_cast<const float2*>(feat)[o2];
            uint a1 = reinterpret_cast<const uint*>(r1)[o2];
            uint a2 = reinterpret_cast<const uint*>(r2)[o2];
            float2 o;
            o.x = f.x + b2f((ushort)a1) + b2f((ushort)a2) + rx;
            o.y = f.y + b2f((ushort)(a1 >> 16)) + b2f((ushort)(a2 >> 16)) + ry;
            reinterpret_cast<float2*>(out)[o2] = o;
        } else {
            uint pk = (uint)f2b(rx) | ((uint)f2b(ry) << 16);
            reinterpret_cast<uint*>(x16_out)[o2] = pk;
            int pk8 = __builtin_amdgcn_cvt_pk_fp8_f32(rx, ry, 0, false);
            x8_out[o2] = (ushort)pk8;
        }
    }
}

// ---------------------------------------------------------------------------

extern "C" void kernel_launch(void* const* d_in, const int* in_sizes, int n_in,
                              void* d_out, int out_size, void* d_ws, size_t ws_size,
                              hipStream_t stream)
{
    const float* feat  = (const float*)d_in[0];
    const float* nbW   = (const float*)d_in[1];
    const float* nbb   = (const float*)d_in[2];
    const float* selfW = (const float*)d_in[3];
    const float* selfb = (const float*)d_in[4];
    const float* a1W   = (const float*)d_in[5];
    const float* a1b   = (const float*)d_in[6];
    const float* a2W   = (const float*)d_in[7];
    const float* a2b   = (const float*)d_in[8];
    const int*   row   = (const int*)d_in[9];
    const int*   col   = (const int*)d_in[10];
    float* out = (float*)d_out;

    const int n = in_sizes[0] / HID;
    const int E = in_sizes[9];
    const int L = in_sizes[1] / (HID * HID);
    const size_t NH = (size_t)n * HID;
    const int K = (n + 255) >> BK;
    const int chunk = (E + B_WG - 1) / B_WG;

    char* p = (char*)d_ws;
    ushort* u          = (ushort*)p; p += NH * 2;
    uchar*  v8         = (uchar*)p;  p += NH;       // v in fp8
    ushort* xf         = (ushort*)p; p += NH * 2;   // bf16(feat)
    ushort* r1         = (ushort*)p; p += NH * 2;   // res layer 1 (bf16)
    ushort* r2         = (ushort*)p; p += NH * 2;   // res layer 2 (bf16)
    ushort* wbuf       = (ushort*)p; p += (size_t)L * 4 * 64 * 68 * 2;
    uchar*  r1_8       = (uchar*)p;  p += NH;       // res layer 1 (fp8)
    uchar*  r2_8       = (uchar*)p;  p += NH;       // res layer 2 (fp8)
    float* dinv        = (float*)p;  p += (size_t)n * 4;
    float* mask_sorted = (float*)p;  p += (size_t)E * 4;
    int*   col_sorted  = (int*)p;    p += (size_t)E * 4;
    int*   row_sorted  = (int*)p;    p += (size_t)E * 4;
    uint*  tmp_rc      = (uint*)p;   p += (size_t)E * 4;
    int*   ptr         = (int*)p;    p += (size_t)(n + 1) * 4;
    int*   hist        = (int*)p;    p += (size_t)KMAX * B_WG * 4;
    int*   offs        = (int*)p;    p += (size_t)KMAX * B_WG * 4;
    int*   bbase       = (int*)p;    p += 1024 * 4;

    const int wBlocks = (int)(((size_t)n * 64 + 255) / 256);
    const int mBlocks = (E + 31) / 32;
    const int nodeBlocks = (n + 127) / 128;

    // ---- one-time prep: weights + CSR radix partition + x bf16 ----
    prep_weights<<<4 * L, 256, 0, stream>>>(nbW, selfW, a1W, wbuf);
    bucket_hist<<<B_WG, 256, 0, stream>>>(row, hist, E, K, chunk);
    bucket_base<<<1, 512, 0, stream>>>(hist, bbase, ptr, K, E, n);
    wg_offsets<<<K, B_WG, 0, stream>>>(hist, bbase, offs);
    partition_edges<<<B_WG, 256, 0, stream>>>(row, col, offs, tmp_rc, E, K, chunk);
    fine_sort<<<K, 256, 0, stream>>>(tmp_rc, bbase, ptr, row_sorted, col_sorted, n);
    cvt_bf16_kernel<<<(int)((NH / 8 + 255) / 256), 256, 0, stream>>>(feat, xf, (long)(NH / 8));

    const ushort* x_in = xf;
    for (int l = 0; l < L; ++l) {
        node_mlp_mfma<<<nodeBlocks, 256, 0, stream>>>(
            x_in, wbuf + (size_t)l * 4 * 64 * 68,
            nbb + (size_t)l * HID, selfb + (size_t)l * HID,
            a1b + (size_t)l * HID,
            u, v8, n);

        edge_mask8<<<mBlocks, 256, 0, stream>>>(
            u, v8, a2W + (size_t)l * HID, a2b + l,
            row_sorted, col_sorted, mask_sorted, E);

        rowsum_dinv<<<(n + 255) / 256, 256, 0, stream>>>(mask_sorted, ptr, dinv, n);

        if (l == 0) {
            agg_csr2<0, false><<<wBlocks, 256, 0, stream>>>(
                xf, nullptr, mask_sorted, dinv, ptr, col_sorted,
                r1, (ushort*)r1_8, nullptr, nullptr, nullptr, nullptr, n);
            x_in = r1;
        } else if (l < L - 1) {
            agg_csr2<1, false><<<wBlocks, 256, 0, stream>>>(
                nullptr, r1_8, mask_sorted, dinv, ptr, col_sorted,
                r2, (ushort*)r2_8, nullptr, nullptr, nullptr, nullptr, n);
            x_in = r2;
        } else {
            agg_csr2<1, true><<<wBlocks, 256, 0, stream>>>(
                nullptr, r2_8, mask_sorted, dinv, ptr, col_sorted,
                nullptr, nullptr, feat, r1, r2, out, n);
        }
    }
}